// Round 18
// baseline (106.743 us; speedup 1.0000x reference)
//
#include <hip/hip_runtime.h>

typedef unsigned short u16;
typedef __bf16 bf16x8 __attribute__((ext_vector_type(8)));
typedef float f32x4 __attribute__((ext_vector_type(4)));

#define S_LEN 2048
#define EMB   1024
#define NHEAD 16
#define HDIM  64
#define WIN   1024

#define AS1 __attribute__((address_space(1)))
#define AS3 __attribute__((address_space(3)))

__device__ __forceinline__ u16 f2bf(float f) {
  unsigned u = __float_as_uint(f);
  u += 0x7FFFu + ((u >> 16) & 1u);   // round-to-nearest-even
  return (u16)(u >> 16);
}

// ---------------- fp32 -> bf16 conversion: 7 tensors, one launch ----------
// (profiled r11: ~10.3us/copy at 83% occupancy ~= BW floor.)
__global__ __launch_bounds__(256) void conv_kernel(
    const float* __restrict__ p0, const float* __restrict__ p1,
    const float* __restrict__ p2, const float* __restrict__ p3,
    const float* __restrict__ p4, const float* __restrict__ p5,
    const float* __restrict__ p6,
    u16* __restrict__ o0, u16* __restrict__ o1, u16* __restrict__ o2,
    u16* __restrict__ o3, u16* __restrict__ o4, u16* __restrict__ o5,
    u16* __restrict__ o6) {
  const float* src; u16* dst; int n;
  switch (blockIdx.y) {
    case 0: src = p0; dst = o0; n = S_LEN * EMB; break;
    case 1: src = p1; dst = o1; n = S_LEN * EMB; break;
    case 2: src = p2; dst = o2; n = S_LEN * EMB; break;
    case 3: src = p3; dst = o3; n = EMB * EMB; break;
    case 4: src = p4; dst = o4; n = EMB * EMB; break;
    case 5: src = p5; dst = o5; n = EMB * EMB; break;
    default: src = p6; dst = o6; n = EMB * EMB; break;
  }
  int i = (blockIdx.x * 256 + threadIdx.x) * 4;
  if (i >= n) return;
  float4 v = *reinterpret_cast<const float4*>(src + i);
  ushort4 r;
  r.x = f2bf(v.x); r.y = f2bf(v.y); r.z = f2bf(v.z); r.w = f2bf(v.w);
  *reinterpret_cast<ushort4*>(dst + i) = r;
}

// ------- bf16 GEMM core, 128x64 tile: C[M,N] = A[M,K] @ W[N,K]^T ----------
__device__ __forceinline__ void gemm_128x64_core(
    const u16* __restrict__ A, const u16* __restrict__ W,
    const float* __restrict__ bias, float scale, int mode,
    u16* __restrict__ outB, float* __restrict__ outF0, float* __restrict__ outF1,
    int N, int K, int bm, int bn, u16* As, u16* Bs) {
  const int tid  = threadIdx.x;
  const int w    = tid >> 6;
  const int lane = tid & 63;
  const int wr = w >> 1, wc = w & 1;
  const int lr = lane & 15;
  const int ko = (lane >> 4) * 8;

  f32x4 acc[4][2];
#pragma unroll
  for (int i = 0; i < 4; ++i)
#pragma unroll
    for (int j = 0; j < 2; ++j) acc[i][j] = f32x4{0.f, 0.f, 0.f, 0.f};

  const int srow = lane >> 3;        // 0..7
  const int scol = (lane & 7) * 8;   // 0..56

  for (int k0 = 0; k0 < K; k0 += 64) {
    const u16* Ab = A + (size_t)bm * K + k0;
    const u16* Wb = W + (size_t)bn * K + k0;
#pragma unroll
    for (int c = 0; c < 4; ++c) {
      int s = w * 4 + c;
      __builtin_amdgcn_global_load_lds(
          (const AS1 void*)(Ab + (size_t)(s * 8 + srow) * K + scol),
          (AS3 void*)(As + s * 512), 16, 0, 0);
    }
#pragma unroll
    for (int c = 0; c < 2; ++c) {
      int s = w * 2 + c;
      __builtin_amdgcn_global_load_lds(
          (const AS1 void*)(Wb + (size_t)(s * 8 + srow) * K + scol),
          (AS3 void*)(Bs + s * 512), 16, 0, 0);
    }
    __syncthreads();
#pragma unroll
    for (int kk = 0; kk < 2; ++kk) {
      bf16x8 af[4], bfr[2];
#pragma unroll
      for (int mi = 0; mi < 4; ++mi)
        af[mi] = *reinterpret_cast<const bf16x8*>(&As[(wr * 64 + mi * 16 + lr) * 64 + kk * 32 + ko]);
#pragma unroll
      for (int ni = 0; ni < 2; ++ni)
        bfr[ni] = *reinterpret_cast<const bf16x8*>(&Bs[(wc * 32 + ni * 16 + lr) * 64 + kk * 32 + ko]);
#pragma unroll
      for (int mi = 0; mi < 4; ++mi)
#pragma unroll
        for (int ni = 0; ni < 2; ++ni)
          acc[mi][ni] = __builtin_amdgcn_mfma_f32_16x16x32_bf16(af[mi], bfr[ni], acc[mi][ni], 0, 0, 0);
    }
    __syncthreads();
  }

  const int cr = (lane >> 4) * 4;
  const int cc = lane & 15;

  if (mode == 2) {
    // transpose epilogue: acc -> LDS [d][row'] (XOR-swizzled) -> Vt [H][D][S]
#pragma unroll
    for (int mi = 0; mi < 4; ++mi) {
#pragma unroll
      for (int ni = 0; ni < 2; ++ni) {
        int dd0 = wc * 32 + ni * 16 + cc;
        float bv = bias[bn + dd0];
#pragma unroll
        for (int r = 0; r < 4; ++r) {
          int rp = wr * 64 + mi * 16 + cr + r;
          As[dd0 * 128 + (rp ^ ((dd0 & 7) * 8))] = f2bf((acc[mi][ni][r] + bv) * scale);
        }
      }
    }
    __syncthreads();
    const int h = bn >> 6;
    u16* Vb = outB + (size_t)h * (HDIM * S_LEN);
    const int dd = tid >> 4;
    const int ch = tid & 15;
#pragma unroll
    for (int i = 0; i < 4; ++i) {
      int d = dd + i * 16;
      const u16* src = &As[d * 128 + ((ch ^ (d & 7)) * 8)];
      u16* dst = Vb + (size_t)d * S_LEN + bm + ch * 8;
      *reinterpret_cast<ushort4*>(dst)     = *reinterpret_cast<const ushort4*>(src);
      *reinterpret_cast<ushort4*>(dst + 4) = *reinterpret_cast<const ushort4*>(src + 4);
    }
    return;
  }

#pragma unroll
  for (int mi = 0; mi < 4; ++mi) {
#pragma unroll
    for (int ni = 0; ni < 2; ++ni) {
      int col = bn + wc * 32 + ni * 16 + cc;
      float bv = bias[col];
#pragma unroll
      for (int r = 0; r < 4; ++r) {
        int row = bm + wr * 64 + mi * 16 + cr + r;
        float val = (acc[mi][ni][r] + bv) * scale;
        if (mode == 1) {
          size_t idx = (size_t)(col >> 6) * (S_LEN * HDIM) + (size_t)row * HDIM + (col & 63);
          outB[idx] = f2bf(val);
        } else {
          outF0[(size_t)row * N + col] = val;
          outF1[(size_t)row * N + col] = val;
        }
      }
    }
  }
}

__device__ __forceinline__ void supertile_decode(int bx, int& bm, int& bn) {
  int sb = bx >> 4, inner = bx & 15;
  bm = ((sb >> 2) * 4 + (inner >> 2)) * 128;
  bn = ((sb & 3) * 4 + (inner & 3)) * 64;
}

// z=0: Q (head-major, pre-scaled 1/64); z=1: K (head-major); z=2: V^T direct
__global__ __launch_bounds__(256, 4) void proj_gemm(
    const u16* __restrict__ Abase, const u16* __restrict__ Wbase,
    const float* __restrict__ b0, const float* __restrict__ b1,
    const float* __restrict__ b2, u16* __restrict__ Qp,
    u16* __restrict__ Kp, u16* __restrict__ Vt) {
  __shared__ u16 As[128 * 64];
  __shared__ u16 Bs[64 * 64];
  const int z = blockIdx.z;
  const u16* A = Abase + (size_t)z * (S_LEN * EMB);
  const u16* W = Wbase + (size_t)z * (EMB * EMB);
  const float* bias = (z == 0) ? b0 : (z == 1 ? b1 : b2);
  u16* O = (z == 0) ? Qp : (z == 1 ? Kp : Vt);
  float scale = (z == 0) ? (1.0f / 64.0f) : 1.0f;
  int bm, bn;
  supertile_decode(blockIdx.x, bm, bn);
  gemm_128x64_core(A, W, bias, scale, (z == 2) ? 2 : 1, O, nullptr, nullptr,
                   EMB, EMB, bm, bn, As, Bs);
}

__global__ __launch_bounds__(256, 4) void out_gemm(
    const u16* __restrict__ A, const u16* __restrict__ W,
    const float* __restrict__ bias, float* __restrict__ out0,
    float* __restrict__ out1) {
  __shared__ u16 As[128 * 64];
  __shared__ u16 Bs[64 * 64];
  int bm, bn;
  supertile_decode(blockIdx.x, bm, bn);
  gemm_128x64_core(A, W, bias, 1.0f, 0, nullptr, out0, out1,
                   EMB, EMB, bm, bn, As, Bs);
}

// ---------------- flash attention: 1-wave blocks, ZERO barriers -----------
// Independence series (r6/r12/r16/r17): perf tracks independent scheduling
// groups per CU. Limit case: 64-thread (1-wave) blocks, 16 q-rows, KVBLK=32,
// LDS 17KB -> 8 independent blocks/CU, NO __syncthreads anywhere. LDS
// producer->consumer ordering is the wave's own counted s_waitcnt vmcnt(10):
// next tile's 8 stage + 2 bias ops stay in flight across the wait (T4,
// finally applicable cleanly: no cross-wave visibility needed). Every stall
// is private to one wave; 7 other resident waves can always issue.
// Swizzles (both sides, rule #21): K rows 128B, chunk^=(row&7) as before;
// V^T/P rows 64B, chunk^=(row&3).
__global__ __launch_bounds__(64, 2) void attn_kernel(
    const u16* __restrict__ Qp, const u16* __restrict__ Kp,
    const u16* __restrict__ Vt, const float* __restrict__ pbias,
    u16* __restrict__ Ob) {
  __shared__ u16 Ks[2][32 * 64];   // K tile [32 tok][64 d], 4KB per buf
  __shared__ u16 Vs[2][64 * 32];   // V^T tile [64 d][32 k], 4KB per buf
  __shared__ u16 Ps[16 * 32];      // P [16 q][32 k], 1KB

  const int lane = threadIdx.x;    // 0..63

  // XCD-aware decode: d = hardware dispatch index (x fastest)
  const int d   = blockIdx.x + 128 * blockIdx.y;  // 0..2047
  const int xcd = d & 7;
  const int s   = d >> 3;                          // 0..255
  const int h   = xcd * 2 + (s >> 7);              // 2 heads per XCD
  const int q0  = (127 - (s & 127)) * 16;          // long blocks first

  const int ql = lane & 15;
  const int g  = lane >> 4;
  const int qg = q0 + ql;
  const int q_hi = q0 + 15;

  const u16* Kh  = Kp + (size_t)h * (S_LEN * HDIM);
  const u16* Vth = Vt + (size_t)h * (HDIM * S_LEN);

  const u16* Qrow = Qp + (size_t)h * (S_LEN * HDIM) + (size_t)qg * HDIM;
  bf16x8 qf0 = *reinterpret_cast<const bf16x8*>(&Qrow[g * 8]);
  bf16x8 qf1 = *reinterpret_cast<const bf16x8*>(&Qrow[32 + g * 8]);

  f32x4 o[4];
#pragma unroll
  for (int i = 0; i < 4; ++i) o[i] = f32x4{0.f, 0.f, 0.f, 0.f};
  float m = -1e30f, l = 0.f;

  const float* brow = pbias + (size_t)h * S_LEN * S_LEN + (size_t)qg * S_LEN + 4 * g;

  int kv_lo = q0 - WIN; if (kv_lo < 0) kv_lo = 0; kv_lo &= ~31;
  const int ntiles = ((q0 + 15 - kv_lo) >> 5) + 1;

  const int swzK = (ql & 7) << 4;
  const int swzP = (ql & 3) << 4;
  char* Prow = (char*)Ps + ql * 64;

  // stage K [32][64] + V^T [64][32] for kv0 into buf: 8 VMEM ops total.
  auto STAGE = [&](int buf, int kv0) {
#pragma unroll
    for (int n = 0; n < 4; ++n) {           // K: 4 instrs, 8 rows each
      int r  = n * 8 + (lane >> 3);
      int cp = (lane & 7) ^ (r & 7);
      __builtin_amdgcn_global_load_lds(
          (const AS1 void*)(Kh + (size_t)(kv0 + r) * HDIM + cp * 8),
          (AS3 void*)(&Ks[buf][n * 512]), 16, 0, 0);
    }
#pragma unroll
    for (int n = 0; n < 4; ++n) {           // V^T: 4 instrs, 16 d-rows each
      int r  = n * 16 + (lane >> 2);
      int cv = (lane & 3) ^ (r & 3);
      __builtin_amdgcn_global_load_lds(
          (const AS1 void*)(Vth + (size_t)r * S_LEN + kv0 + cv * 8),
          (AS3 void*)(&Vs[buf][n * 512]), 16, 0, 0);
    }
  };

  STAGE(0, kv_lo);
  float4 nb0 = *reinterpret_cast<const float4*>(&brow[kv_lo]);
  float4 nb1 = *reinterpret_cast<const float4*>(&brow[kv_lo + 16]);
  int cur = 0;

  for (int t = 0; t < ntiles; ++t) {
    const int kv0 = kv_lo + t * 32;
    const int nxt = (t + 1 < ntiles) ? kv0 + 32 : kv_lo;  // clamped, uniform

    STAGE(cur ^ 1, nxt);                    // 8 ops in flight
    float4 cb0 = nb0, cb1 = nb1;            // bias(t): compiler-waited
    nb0 = *reinterpret_cast<const float4*>(&brow[nxt]);        // +2 ops
    nb1 = *reinterpret_cast<const float4*>(&brow[nxt + 16]);

    // stage(t) landed; stage(t+1)+bias(t+1) = 10 newest stay in flight
    asm volatile("s_waitcnt vmcnt(10)" ::: "memory");
    __builtin_amdgcn_sched_barrier(0);

    const char* Kl = (const char*)&Ks[cur][0];
    const char* Vl = (const char*)&Vs[cur][0];

    // ---- QK^T (swapped): C col=q(ql), row=k(4g+r within 16) ----
    f32x4 s4[2];
#pragma unroll
    for (int kt = 0; kt < 2; ++kt) {
      bf16x8 ka  = *reinterpret_cast<const bf16x8*>(Kl + (kt * 16 + ql) * 128 + ((g * 16) ^ swzK));
      bf16x8 kb2 = *reinterpret_cast<const bf16x8*>(Kl + (kt * 16 + ql) * 128 + ((64 + g * 16) ^ swzK));
      f32x4 acc = f32x4{0.f, 0.f, 0.f, 0.f};
      acc = __builtin_amdgcn_mfma_f32_16x16x32_bf16(ka,  qf0, acc, 0, 0, 0);
      acc = __builtin_amdgcn_mfma_f32_16x16x32_bf16(kb2, qf1, acc, 0, 0, 0);
      s4[kt] = acc;
    }

    // ---- bias + mask + online softmax over 32 cols ----
    const bool full = (kv0 + 31 <= q0) && (q_hi - kv0 <= WIN);
    float bv[2][4] = {{cb0.x, cb0.y, cb0.z, cb0.w},
                      {cb1.x, cb1.y, cb1.z, cb1.w}};
    float lmax = -INFINITY;
#pragma unroll
    for (int kt = 0; kt < 2; ++kt)
#pragma unroll
      for (int r = 0; r < 4; ++r) {
        int k = kv0 + kt * 16 + 4 * g + r;
        float xv = s4[kt][r] + bv[kt][r];
        if (!full) {
          bool ok = (k <= qg) && ((qg - k) <= WIN);
          xv = ok ? xv : -INFINITY;
        }
        s4[kt][r] = xv;
        lmax = fmaxf(lmax, xv);
      }
    lmax = fmaxf(lmax, __shfl_xor(lmax, 16));
    lmax = fmaxf(lmax, __shfl_xor(lmax, 32));
    float mn = fmaxf(m, lmax);
    float corr = __expf(m - mn);
    m = mn;
    float ls = 0.f;
#pragma unroll
    for (int kt = 0; kt < 2; ++kt)
#pragma unroll
      for (int r = 0; r < 4; ++r) {
        float e = __expf(s4[kt][r] - mn);
        s4[kt][r] = e;
        ls += e;
      }
    ls += __shfl_xor(ls, 16);
    ls += __shfl_xor(ls, 32);
    l = l * corr + ls;
#pragma unroll
    for (int dt = 0; dt < 4; ++dt) {
      f32x4 tt = o[dt];
#pragma unroll
      for (int r = 0; r < 4; ++r) tt[r] *= corr;
      o[dt] = tt;
    }

    // ---- P -> LDS (row=q, 64B rows, swizzled), PV from LDS V^T ----
#pragma unroll
    for (int kt = 0; kt < 2; ++kt) {
      ushort4 pw;
      pw.x = f2bf(s4[kt][0]); pw.y = f2bf(s4[kt][1]);
      pw.z = f2bf(s4[kt][2]); pw.w = f2bf(s4[kt][3]);
      *reinterpret_cast<ushort4*>(Prow + ((kt * 32 + g * 8) ^ swzP)) = pw;
    }
    bf16x8 pf = *reinterpret_cast<const bf16x8*>(Prow + ((g * 16) ^ swzP));
    const int vchunk = (g ^ (ql & 3)) * 16;
#pragma unroll
    for (int dt = 0; dt < 4; ++dt) {
      bf16x8 vf = *reinterpret_cast<const bf16x8*>(Vl + (dt * 16 + ql) * 64 + vchunk);
      o[dt] = __builtin_amdgcn_mfma_f32_16x16x32_bf16(vf, pf, o[dt], 0, 0, 0);
    }
    cur ^= 1;
  }

  float inv = (l > 0.f) ? 1.f / l : 0.f;
  u16* op = &Ob[(size_t)qg * EMB + h * HDIM];
#pragma unroll
  for (int dt = 0; dt < 4; ++dt) {
    ushort4 outv;
#pragma unroll
    for (int r = 0; r < 4; ++r) ((u16*)&outv)[r] = f2bf(o[dt][r] * inv);
    *reinterpret_cast<ushort4*>(op + dt * 16 + 4 * g) = outv;
  }
}

// --------------------------------------------------------------------------
extern "C" void kernel_launch(void* const* d_in, const int* in_sizes, int n_in,
                              void* d_out, int out_size, void* d_ws, size_t ws_size,
                              hipStream_t stream) {
  (void)in_sizes; (void)n_in; (void)out_size; (void)ws_size;
  const float* q  = (const float*)d_in[0];
  const float* k  = (const float*)d_in[1];
  const float* v  = (const float*)d_in[2];
  const float* pb = (const float*)d_in[3];
  const float* Wq = (const float*)d_in[4];
  const float* bq = (const float*)d_in[5];
  const float* Wk = (const float*)d_in[6];
  const float* bk = (const float*)d_in[7];
  const float* Wv = (const float*)d_in[8];
  const float* bv = (const float*)d_in[9];
  const float* Wo = (const float*)d_in[10];
  const float* bo = (const float*)d_in[11];
  float* out = (float*)d_out;

  const size_t SE = (size_t)S_LEN * EMB;
  const size_t EE = (size_t)EMB * EMB;
  u16* ws  = (u16*)d_ws;
  u16* qb  = ws;
  u16* kb  = qb + SE;
  u16* vb  = kb + SE;
  u16* wqb = vb + SE;
  u16* wkb = wqb + EE;
  u16* wvb = wkb + EE;
  u16* wob = wvb + EE;
  u16* Qp  = wob + EE;        // [H][S][D], pre-scaled 1/64
  u16* Kp  = Qp + SE;         // [H][S][D]
  u16* Vt  = Kp + SE;         // [H][D][S] (written directly by proj z=2)
  u16* Ob  = Vt + SE;         // [S][E]

  conv_kernel<<<dim3(2048, 7), 256, 0, stream>>>(q, k, v, Wq, Wk, Wv, Wo,
                                                 qb, kb, vb, wqb, wkb, wvb, wob);
  proj_gemm<<<dim3(256, 1, 3), 256, 0, stream>>>(qb, wqb, bq, bk, bv, Qp, Kp, Vt);
  attn_kernel<<<dim3(128, 16), 64, 0, stream>>>(Qp, Kp, Vt, pb, Ob);
  out_gemm<<<dim3(256), 256, 0, stream>>>(Ob, wob, bo, out, out + SE);
}

// Round 19
// 95.638 us; speedup vs baseline: 1.1161x; 1.1161x over previous
//
#include <hip/hip_runtime.h>

typedef unsigned short u16;
typedef __bf16 bf16x8 __attribute__((ext_vector_type(8)));
typedef float f32x4 __attribute__((ext_vector_type(4)));

#define S_LEN 2048
#define EMB   1024
#define NHEAD 16
#define HDIM  64
#define WIN   1024

#define AS1 __attribute__((address_space(1)))
#define AS3 __attribute__((address_space(3)))

__device__ __forceinline__ u16 f2bf(float f) {
  unsigned u = __float_as_uint(f);
  u += 0x7FFFu + ((u >> 16) & 1u);   // round-to-nearest-even
  return (u16)(u >> 16);
}

// ---------------- fp32 -> bf16 conversion: 7 tensors, one launch ----------
// (profiled r11: ~10.3us/copy at 83% occupancy ~= BW floor.)
__global__ __launch_bounds__(256) void conv_kernel(
    const float* __restrict__ p0, const float* __restrict__ p1,
    const float* __restrict__ p2, const float* __restrict__ p3,
    const float* __restrict__ p4, const float* __restrict__ p5,
    const float* __restrict__ p6,
    u16* __restrict__ o0, u16* __restrict__ o1, u16* __restrict__ o2,
    u16* __restrict__ o3, u16* __restrict__ o4, u16* __restrict__ o5,
    u16* __restrict__ o6) {
  const float* src; u16* dst; int n;
  switch (blockIdx.y) {
    case 0: src = p0; dst = o0; n = S_LEN * EMB; break;
    case 1: src = p1; dst = o1; n = S_LEN * EMB; break;
    case 2: src = p2; dst = o2; n = S_LEN * EMB; break;
    case 3: src = p3; dst = o3; n = EMB * EMB; break;
    case 4: src = p4; dst = o4; n = EMB * EMB; break;
    case 5: src = p5; dst = o5; n = EMB * EMB; break;
    default: src = p6; dst = o6; n = EMB * EMB; break;
  }
  int i = (blockIdx.x * 256 + threadIdx.x) * 4;
  if (i >= n) return;
  float4 v = *reinterpret_cast<const float4*>(src + i);
  ushort4 r;
  r.x = f2bf(v.x); r.y = f2bf(v.y); r.z = f2bf(v.z); r.w = f2bf(v.w);
  *reinterpret_cast<ushort4*>(dst + i) = r;
}

// ------- bf16 GEMM core, 128x64 tile: C[M,N] = A[M,K] @ W[N,K]^T ----------
__device__ __forceinline__ void gemm_128x64_core(
    const u16* __restrict__ A, const u16* __restrict__ W,
    const float* __restrict__ bias, float scale, int mode,
    u16* __restrict__ outB, float* __restrict__ outF0, float* __restrict__ outF1,
    int N, int K, int bm, int bn, u16* As, u16* Bs) {
  const int tid  = threadIdx.x;
  const int w    = tid >> 6;
  const int lane = tid & 63;
  const int wr = w >> 1, wc = w & 1;
  const int lr = lane & 15;
  const int ko = (lane >> 4) * 8;

  f32x4 acc[4][2];
#pragma unroll
  for (int i = 0; i < 4; ++i)
#pragma unroll
    for (int j = 0; j < 2; ++j) acc[i][j] = f32x4{0.f, 0.f, 0.f, 0.f};

  const int srow = lane >> 3;        // 0..7
  const int scol = (lane & 7) * 8;   // 0..56

  for (int k0 = 0; k0 < K; k0 += 64) {
    const u16* Ab = A + (size_t)bm * K + k0;
    const u16* Wb = W + (size_t)bn * K + k0;
#pragma unroll
    for (int c = 0; c < 4; ++c) {
      int s = w * 4 + c;
      __builtin_amdgcn_global_load_lds(
          (const AS1 void*)(Ab + (size_t)(s * 8 + srow) * K + scol),
          (AS3 void*)(As + s * 512), 16, 0, 0);
    }
#pragma unroll
    for (int c = 0; c < 2; ++c) {
      int s = w * 2 + c;
      __builtin_amdgcn_global_load_lds(
          (const AS1 void*)(Wb + (size_t)(s * 8 + srow) * K + scol),
          (AS3 void*)(Bs + s * 512), 16, 0, 0);
    }
    __syncthreads();
#pragma unroll
    for (int kk = 0; kk < 2; ++kk) {
      bf16x8 af[4], bfr[2];
#pragma unroll
      for (int mi = 0; mi < 4; ++mi)
        af[mi] = *reinterpret_cast<const bf16x8*>(&As[(wr * 64 + mi * 16 + lr) * 64 + kk * 32 + ko]);
#pragma unroll
      for (int ni = 0; ni < 2; ++ni)
        bfr[ni] = *reinterpret_cast<const bf16x8*>(&Bs[(wc * 32 + ni * 16 + lr) * 64 + kk * 32 + ko]);
#pragma unroll
      for (int mi = 0; mi < 4; ++mi)
#pragma unroll
        for (int ni = 0; ni < 2; ++ni)
          acc[mi][ni] = __builtin_amdgcn_mfma_f32_16x16x32_bf16(af[mi], bfr[ni], acc[mi][ni], 0, 0, 0);
    }
    __syncthreads();
  }

  const int cr = (lane >> 4) * 4;
  const int cc = lane & 15;

  if (mode == 2) {
    // transpose epilogue: acc -> LDS [d][row'] (XOR-swizzled) -> Vt [H][D][S]
#pragma unroll
    for (int mi = 0; mi < 4; ++mi) {
#pragma unroll
      for (int ni = 0; ni < 2; ++ni) {
        int dd0 = wc * 32 + ni * 16 + cc;
        float bv = bias[bn + dd0];
#pragma unroll
        for (int r = 0; r < 4; ++r) {
          int rp = wr * 64 + mi * 16 + cr + r;
          As[dd0 * 128 + (rp ^ ((dd0 & 7) * 8))] = f2bf((acc[mi][ni][r] + bv) * scale);
        }
      }
    }
    __syncthreads();
    const int h = bn >> 6;
    u16* Vb = outB + (size_t)h * (HDIM * S_LEN);
    const int dd = tid >> 4;
    const int ch = tid & 15;
#pragma unroll
    for (int i = 0; i < 4; ++i) {
      int d = dd + i * 16;
      const u16* src = &As[d * 128 + ((ch ^ (d & 7)) * 8)];
      u16* dst = Vb + (size_t)d * S_LEN + bm + ch * 8;
      *reinterpret_cast<ushort4*>(dst)     = *reinterpret_cast<const ushort4*>(src);
      *reinterpret_cast<ushort4*>(dst + 4) = *reinterpret_cast<const ushort4*>(src + 4);
    }
    return;
  }

#pragma unroll
  for (int mi = 0; mi < 4; ++mi) {
#pragma unroll
    for (int ni = 0; ni < 2; ++ni) {
      int col = bn + wc * 32 + ni * 16 + cc;
      float bv = bias[col];
#pragma unroll
      for (int r = 0; r < 4; ++r) {
        int row = bm + wr * 64 + mi * 16 + cr + r;
        float val = (acc[mi][ni][r] + bv) * scale;
        if (mode == 1) {
          size_t idx = (size_t)(col >> 6) * (S_LEN * HDIM) + (size_t)row * HDIM + (col & 63);
          outB[idx] = f2bf(val);
        } else {
          outF0[(size_t)row * N + col] = val;
          outF1[(size_t)row * N + col] = val;
        }
      }
    }
  }
}

__device__ __forceinline__ void supertile_decode(int bx, int& bm, int& bn) {
  int sb = bx >> 4, inner = bx & 15;
  bm = ((sb >> 2) * 4 + (inner >> 2)) * 128;
  bn = ((sb & 3) * 4 + (inner & 3)) * 64;
}

// z=0: Q (head-major, pre-scaled 1/64); z=1: K (head-major); z=2: V^T direct
__global__ __launch_bounds__(256, 4) void proj_gemm(
    const u16* __restrict__ Abase, const u16* __restrict__ Wbase,
    const float* __restrict__ b0, const float* __restrict__ b1,
    const float* __restrict__ b2, u16* __restrict__ Qp,
    u16* __restrict__ Kp, u16* __restrict__ Vt) {
  __shared__ u16 As[128 * 64];
  __shared__ u16 Bs[64 * 64];
  const int z = blockIdx.z;
  const u16* A = Abase + (size_t)z * (S_LEN * EMB);
  const u16* W = Wbase + (size_t)z * (EMB * EMB);
  const float* bias = (z == 0) ? b0 : (z == 1 ? b1 : b2);
  u16* O = (z == 0) ? Qp : (z == 1 ? Kp : Vt);
  float scale = (z == 0) ? (1.0f / 64.0f) : 1.0f;
  int bm, bn;
  supertile_decode(blockIdx.x, bm, bn);
  gemm_128x64_core(A, W, bias, scale, (z == 2) ? 2 : 1, O, nullptr, nullptr,
                   EMB, EMB, bm, bn, As, Bs);
}

__global__ __launch_bounds__(256, 4) void out_gemm(
    const u16* __restrict__ A, const u16* __restrict__ W,
    const float* __restrict__ bias, float* __restrict__ out0,
    float* __restrict__ out1) {
  __shared__ u16 As[128 * 64];
  __shared__ u16 Bs[64 * 64];
  int bm, bn;
  supertile_decode(blockIdx.x, bm, bn);
  gemm_128x64_core(A, W, bias, 1.0f, 0, nullptr, out0, out1,
                   EMB, EMB, bm, bn, As, Bs);
}

// ---------------- flash attention: 2-wave blocks, 4 independent/CU --------
// r17 optimum of the independence series (r6/r12/r16/r17/r18): 128-thread
// (2-wave) blocks, 32 q-rows each, 1024 blocks, LDS 36KB -> 4 independent
// blocks/CU with cheap 2-wave barriers. Bias cross-barrier double-buffer;
// XCD map: 128 blocks/XCD = 2 complete heads; long-q0 first within head.
__global__ __launch_bounds__(128, 2) void attn_kernel(
    const u16* __restrict__ Qp, const u16* __restrict__ Kp,
    const u16* __restrict__ Vt, const float* __restrict__ pbias,
    u16* __restrict__ Ob) {
  __shared__ u16 KV[2][2][64 * 64];   // [buf][0=K tile / 1=V^T tile] 32KB
  __shared__ u16 Pb[2][16 * 64];      // per-wave P buffer (swizzled) 4KB

  const int tid  = threadIdx.x;
  const int w    = tid >> 6;           // 0..1
  const int lane = tid & 63;

  // XCD-aware decode: d = hardware dispatch index (x fastest)
  const int d   = blockIdx.x + 64 * blockIdx.y;   // 0..1023
  const int xcd = d & 7;
  const int s   = d >> 3;                          // 0..127
  const int h   = xcd * 2 + (s >> 6);              // 2 heads per XCD
  const int q0  = (63 - (s & 63)) * 32;            // long blocks first

  const int ql = lane & 15;
  const int g  = lane >> 4;
  const int qw = q0 + w * 16;
  const int qg = qw + ql;
  const int qw_hi = qw + 15;

  const u16* Kh  = Kp + (size_t)h * (S_LEN * HDIM);
  const u16* Vth = Vt + (size_t)h * (HDIM * S_LEN);

  const u16* Qrow = Qp + (size_t)h * (S_LEN * HDIM) + (size_t)qg * HDIM;
  bf16x8 qf0 = *reinterpret_cast<const bf16x8*>(&Qrow[g * 8]);
  bf16x8 qf1 = *reinterpret_cast<const bf16x8*>(&Qrow[32 + g * 8]);

  f32x4 o[4];
#pragma unroll
  for (int i = 0; i < 4; ++i) o[i] = f32x4{0.f, 0.f, 0.f, 0.f};
  float m = -1e30f, l = 0.f;

  const float* brow = pbias + (size_t)h * S_LEN * S_LEN + (size_t)qg * S_LEN + 4 * g;

  int kv_lo = q0 - WIN; if (kv_lo < 0) kv_lo = 0; kv_lo &= ~63;
  const int ntiles = ((q0 + 31 - kv_lo) >> 6) + 1;
  const int kv_last = kv_lo + (ntiles - 1) * 64;

  const int swz = (ql & 7) << 4;
  char* Prow = (char*)&Pb[w][0] + ql * 128;

  // wave w stages K rows [w*32, w*32+32) and V^T rows [w*32, w*32+32).
  auto STAGE = [&](int buf, int kv0) {
    u16* Kd = &KV[buf][0][(w * 32) * 64];
    u16* Vd = &KV[buf][1][(w * 32) * 64];
#pragma unroll
    for (int n = 0; n < 4; ++n) {
      int r  = w * 32 + n * 8 + (lane >> 3);
      int cp = (lane & 7) ^ (r & 7);
      __builtin_amdgcn_global_load_lds(
          (const AS1 void*)(Kh + (size_t)(kv0 + r) * HDIM + cp * 8),
          (AS3 void*)(Kd + n * 512), 16, 0, 0);
      __builtin_amdgcn_global_load_lds(
          (const AS1 void*)(Vth + (size_t)r * S_LEN + kv0 + cp * 8),
          (AS3 void*)(Vd + n * 512), 16, 0, 0);
    }
  };

  STAGE(0, kv_lo);
  float4 nb[4], cb[4];
#pragma unroll
  for (int kt = 0; kt < 4; ++kt)
    nb[kt] = *reinterpret_cast<const float4*>(&brow[kv_lo + kt * 16]);
  int cur = 0;

  for (int t = 0; t < ntiles; ++t) {
    const int kv0 = kv_lo + t * 64;
    __syncthreads();            // buf[cur] staged AND nb loads drained
#pragma unroll
    for (int kt = 0; kt < 4; ++kt) cb[kt] = nb[kt];

    if (t + 1 < ntiles) STAGE(cur ^ 1, kv0 + 64);
    const int nxt = (kv0 + 64 <= kv_last) ? kv0 + 64 : kv0;
#pragma unroll
    for (int kt = 0; kt < 4; ++kt)
      nb[kt] = *reinterpret_cast<const float4*>(&brow[nxt + kt * 16]);

    const bool active = (kv0 <= qw_hi) && (kv0 + 63 >= qw - WIN);
    if (active) {
      const char* Kl = (const char*)&KV[cur][0][0];
      const char* Vl = (const char*)&KV[cur][1][0];

      // ---- QK^T (swapped): C col=q(ql), row=k(4g+r within 16) ----
      f32x4 s4[4];
#pragma unroll
      for (int kt = 0; kt < 4; ++kt) {
        bf16x8 ka = *reinterpret_cast<const bf16x8*>(Kl + (kt * 16 + ql) * 128 + ((g * 16) ^ swz));
        bf16x8 kb = *reinterpret_cast<const bf16x8*>(Kl + (kt * 16 + ql) * 128 + ((64 + g * 16) ^ swz));
        f32x4 acc = f32x4{0.f, 0.f, 0.f, 0.f};
        acc = __builtin_amdgcn_mfma_f32_16x16x32_bf16(ka, qf0, acc, 0, 0, 0);
        acc = __builtin_amdgcn_mfma_f32_16x16x32_bf16(kb, qf1, acc, 0, 0, 0);
        s4[kt] = acc;
      }

      // ---- bias + mask + online softmax (cb already in registers) ----
      const bool full = (kv0 + 63 <= qw) && (qw_hi - kv0 <= WIN);
      float lmax = -INFINITY;
#pragma unroll
      for (int kt = 0; kt < 4; ++kt) {
        float bvr[4] = {cb[kt].x, cb[kt].y, cb[kt].z, cb[kt].w};
#pragma unroll
        for (int r = 0; r < 4; ++r) {
          int k = kv0 + kt * 16 + 4 * g + r;
          float xv = s4[kt][r] + bvr[r];
          if (!full) {
            bool ok = (k <= qg) && ((qg - k) <= WIN);
            xv = ok ? xv : -INFINITY;
          }
          s4[kt][r] = xv;
          lmax = fmaxf(lmax, xv);
        }
      }
      lmax = fmaxf(lmax, __shfl_xor(lmax, 16));
      lmax = fmaxf(lmax, __shfl_xor(lmax, 32));
      float mn = fmaxf(m, lmax);
      float corr = __expf(m - mn);
      m = mn;
      float ls = 0.f;
#pragma unroll
      for (int kt = 0; kt < 4; ++kt)
#pragma unroll
        for (int r = 0; r < 4; ++r) {
          float e = __expf(s4[kt][r] - mn);
          s4[kt][r] = e;
          ls += e;
        }
      ls += __shfl_xor(ls, 16);
      ls += __shfl_xor(ls, 32);
      l = l * corr + ls;
#pragma unroll
      for (int dt = 0; dt < 4; ++dt) {
        f32x4 tt = o[dt];
#pragma unroll
        for (int r = 0; r < 4; ++r) tt[r] *= corr;
        o[dt] = tt;
      }

      // ---- P -> LDS (row=q, swizzled), PV from LDS V^T ----
#pragma unroll
      for (int kt = 0; kt < 4; ++kt) {
        ushort4 pw;
        pw.x = f2bf(s4[kt][0]); pw.y = f2bf(s4[kt][1]);
        pw.z = f2bf(s4[kt][2]); pw.w = f2bf(s4[kt][3]);
        *reinterpret_cast<ushort4*>(Prow + ((kt * 32 + g * 8) ^ swz)) = pw;
      }
#pragma unroll
      for (int kb = 0; kb < 2; ++kb) {
        bf16x8 pf = *reinterpret_cast<const bf16x8*>(Prow + ((kb * 64 + g * 16) ^ swz));
#pragma unroll
        for (int dt = 0; dt < 4; ++dt) {
          bf16x8 vf = *reinterpret_cast<const bf16x8*>(Vl + (dt * 16 + ql) * 128 + ((kb * 64 + g * 16) ^ swz));
          o[dt] = __builtin_amdgcn_mfma_f32_16x16x32_bf16(vf, pf, o[dt], 0, 0, 0);
        }
      }
    }
    cur ^= 1;
  }

  float inv = (l > 0.f) ? 1.f / l : 0.f;
  u16* op = &Ob[(size_t)qg * EMB + h * HDIM];
#pragma unroll
  for (int dt = 0; dt < 4; ++dt) {
    ushort4 outv;
#pragma unroll
    for (int r = 0; r < 4; ++r) ((u16*)&outv)[r] = f2bf(o[dt][r] * inv);
    *reinterpret_cast<ushort4*>(op + dt * 16 + 4 * g) = outv;
  }
}

// --------------------------------------------------------------------------
extern "C" void kernel_launch(void* const* d_in, const int* in_sizes, int n_in,
                              void* d_out, int out_size, void* d_ws, size_t ws_size,
                              hipStream_t stream) {
  (void)in_sizes; (void)n_in; (void)out_size; (void)ws_size;
  const float* q  = (const float*)d_in[0];
  const float* k  = (const float*)d_in[1];
  const float* v  = (const float*)d_in[2];
  const float* pb = (const float*)d_in[3];
  const float* Wq = (const float*)d_in[4];
  const float* bq = (const float*)d_in[5];
  const float* Wk = (const float*)d_in[6];
  const float* bk = (const float*)d_in[7];
  const float* Wv = (const float*)d_in[8];
  const float* bv = (const float*)d_in[9];
  const float* Wo = (const float*)d_in[10];
  const float* bo = (const float*)d_in[11];
  float* out = (float*)d_out;

  const size_t SE = (size_t)S_LEN * EMB;
  const size_t EE = (size_t)EMB * EMB;
  u16* ws  = (u16*)d_ws;
  u16* qb  = ws;
  u16* kb  = qb + SE;
  u16* vb  = kb + SE;
  u16* wqb = vb + SE;
  u16* wkb = wqb + EE;
  u16* wvb = wkb + EE;
  u16* wob = wvb + EE;
  u16* Qp  = wob + EE;        // [H][S][D], pre-scaled 1/64
  u16* Kp  = Qp + SE;         // [H][S][D]
  u16* Vt  = Kp + SE;         // [H][D][S] (written directly by proj z=2)
  u16* Ob  = Vt + SE;         // [S][E]

  conv_kernel<<<dim3(2048, 7), 256, 0, stream>>>(q, k, v, Wq, Wk, Wv, Wo,
                                                 qb, kb, vb, wqb, wkb, wvb, wob);
  proj_gemm<<<dim3(256, 1, 3), 256, 0, stream>>>(qb, wqb, bq, bk, bv, Qp, Kp, Vt);
  attn_kernel<<<dim3(64, 16), 128, 0, stream>>>(Qp, Kp, Vt, pb, Ob);
  out_gemm<<<dim3(256), 256, 0, stream>>>(Ob, wob, bo, out, out + SE);
}